// Round 2
// baseline (232756.958 us; speedup 1.0000x reference)
//
#include <hip/hip_runtime.h>
#include <cstdint>
#include <cstddef>

#define TPB 1024
#define NB  256

typedef float4 f4;

// ---------------- JAX Threefry-2x32 (partitionable variant) ----------------
__device__ __forceinline__ void tf2x32(uint32_t k0, uint32_t k1, uint32_t x0, uint32_t x1,
                                       uint32_t& o0, uint32_t& o1) {
  uint32_t ks2 = k0 ^ k1 ^ 0x1BD11BDAu;
  x0 += k0; x1 += k1;
#define TFR(r) { x0 += x1; x1 = (x1 << (r)) | (x1 >> (32 - (r))); x1 ^= x0; }
  TFR(13) TFR(15) TFR(26) TFR(6)
  x0 += k1;  x1 += ks2 + 1u;
  TFR(17) TFR(29) TFR(16) TFR(24)
  x0 += ks2; x1 += k0 + 2u;
  TFR(13) TFR(15) TFR(26) TFR(6)
  x0 += k0;  x1 += k1 + 3u;
  TFR(17) TFR(29) TFR(16) TFR(24)
  x0 += k1;  x1 += ks2 + 4u;
  TFR(13) TFR(15) TFR(26) TFR(6)
  x0 += ks2; x1 += k0 + 5u;
#undef TFR
  o0 = x0; o1 = x1;
}

__device__ __forceinline__ uint32_t tf_fold(uint32_t k0, uint32_t k1, uint32_t idx) {
  uint32_t a, b; tf2x32(k0, k1, 0u, idx, a, b); return a ^ b;
}

// ---------------- helpers ----------------
__device__ __forceinline__ float dot4(f4 a, f4 b, float acc) {
  acc = fmaf(a.x, b.x, acc); acc = fmaf(a.y, b.y, acc);
  acc = fmaf(a.z, b.z, acc); acc = fmaf(a.w, b.w, acc);
  return acc;
}

__device__ __forceinline__ float dot_f4(const float* __restrict__ x, const float* __restrict__ w, int n4) {
  const f4* xv = (const f4*)x; const f4* wv = (const f4*)w;
  float s = 0.f;
#pragma unroll 8
  for (int k = 0; k < n4; ++k) s = dot4(xv[k], wv[k], s);
  return s;
}

__device__ __forceinline__ float sigm(float x) { return 1.f / (1.f + expf(-x)); }

__device__ __forceinline__ float wave_sum(float s) {
#pragma unroll
  for (int off = 32; off; off >>= 1) s += __shfl_xor(s, off, 64);
  return s;
}

__device__ __forceinline__ void grid_sync(unsigned* bar) {
  __syncthreads();
  if (threadIdx.x == 0) {
    __threadfence();
    unsigned g = __hip_atomic_load(bar + 1, __ATOMIC_RELAXED, __HIP_MEMORY_SCOPE_AGENT);
    unsigned a = __hip_atomic_fetch_add(bar, 1u, __ATOMIC_ACQ_REL, __HIP_MEMORY_SCOPE_AGENT);
    if (a == (unsigned)(NB - 1)) {
      __hip_atomic_store(bar, 0u, __ATOMIC_RELAXED, __HIP_MEMORY_SCOPE_AGENT);
      __hip_atomic_store(bar + 1, g + 1u, __ATOMIC_RELEASE, __HIP_MEMORY_SCOPE_AGENT);
    } else {
      while (__hip_atomic_load(bar + 1, __ATOMIC_ACQUIRE, __HIP_MEMORY_SCOPE_AGENT) == g)
        __builtin_amdgcn_s_sleep(1);
    }
  }
  __syncthreads();
}

// ws layout (floats)
#define WS_AH   16
#define WS_AC   (WS_AH + 32768)
#define WS_DH   (WS_AC + 16384)
#define WS_DC   (WS_DH + 32768)
#define WS_ACTX (WS_DC + 16384)
#define WS_DEC  (WS_ACTX + 16384)
#define WS_PMEM (WS_DEC + 819200)
#define WS_STATE_BYTES (WS_DEC * 4)

// ---- LSTM gate GEMM, K-sliced: wave=(batch-pair, row-half), lane=f4 k-slice ----
// Attention-LSTM: K = 1792 = [dec 256 | actx 512 | ah 1024]; W = a_wih(row x 768) ++ a_whh(row x 1024)
__device__ __forceinline__ void lstmA_gates(int tid, int jbase,
    const float* __restrict__ dec_t, const float* __restrict__ actx_p, const float* __restrict__ ah_p,
    const float* __restrict__ a_wih, const float* __restrict__ a_whh, float* __restrict__ gates) {
  const int wid = tid >> 6, l = tid & 63;
  const int bp = wid & 7, rh = wid >> 3;
  const int b0 = bp * 2, b1 = b0 + 1;
  f4 x0[7], x1[7];
#pragma unroll
  for (int c = 0; c < 7; ++c) {
    const int kf = l + 64 * c;
    const float *p0, *p1;
    if (c == 0)      { p0 = dec_t  + b0 * 256  + kf * 4;         p1 = dec_t  + b1 * 256  + kf * 4; }
    else if (c <= 2) { p0 = actx_p + b0 * 512  + (kf - 64) * 4;  p1 = actx_p + b1 * 512  + (kf - 64) * 4; }
    else             { p0 = ah_p   + b0 * 1024 + (kf - 192) * 4; p1 = ah_p   + b1 * 1024 + (kf - 192) * 4; }
    x0[c] = *(const f4*)p0; x1[c] = *(const f4*)p1;
  }
  float a0[8], a1[8];
#pragma unroll
  for (int rr = 0; rr < 8; ++rr) { a0[rr] = 0.f; a1[rr] = 0.f; }
#pragma unroll
  for (int rr = 0; rr < 8; ++rr) {
    const int rl = rh * 8 + rr;
    const int row = (rl & 3) * 1024 + jbase + (rl >> 2);
    const f4* wih = (const f4*)(a_wih + (size_t)row * 768);
    const f4* whh = (const f4*)(a_whh + (size_t)row * 1024);
#pragma unroll
    for (int c = 0; c < 7; ++c) {
      f4 w = (c < 3) ? wih[l + 64 * c] : whh[l + 64 * c - 192];
      a0[rr] = dot4(w, x0[c], a0[rr]);
      a1[rr] = dot4(w, x1[c], a1[rr]);
    }
  }
#pragma unroll
  for (int rr = 0; rr < 8; ++rr) {
    float s0 = wave_sum(a0[rr]);
    float s1 = wave_sum(a1[rr]);
    if (l == 0) {
      gates[(rh * 8 + rr) * 16 + b0] = s0;
      gates[(rh * 8 + rr) * 16 + b1] = s1;
    }
  }
}

// Decoder-LSTM: K = 2560 = [ah 1024 | actx 512 | dh 1024]; W = d_wih(row x 1536) ++ d_whh(row x 1024)
__device__ __forceinline__ void lstmC_gates(int tid, int jbase,
    const float* __restrict__ ahc, const float* __restrict__ axc, const float* __restrict__ dhp,
    const float* __restrict__ d_wih, const float* __restrict__ d_whh, float* __restrict__ gates) {
  const int wid = tid >> 6, l = tid & 63;
  const int bp = wid & 7, rh = wid >> 3;
  const int b0 = bp * 2, b1 = b0 + 1;
  float a0[8], a1[8];
#pragma unroll
  for (int rr = 0; rr < 8; ++rr) { a0[rr] = 0.f; a1[rr] = 0.f; }
#pragma unroll
  for (int h = 0; h < 2; ++h) {
    f4 x0[5], x1[5];
#pragma unroll
    for (int ci = 0; ci < 5; ++ci) {
      const int c = h * 5 + ci;
      const int kf = l + 64 * c;
      const float *p0, *p1;
      if (c < 4)      { p0 = ahc + b0 * 1024 + kf * 4;         p1 = ahc + b1 * 1024 + kf * 4; }
      else if (c < 6) { p0 = axc + b0 * 512  + (kf - 256) * 4; p1 = axc + b1 * 512  + (kf - 256) * 4; }
      else            { p0 = dhp + b0 * 1024 + (kf - 384) * 4; p1 = dhp + b1 * 1024 + (kf - 384) * 4; }
      x0[ci] = *(const f4*)p0; x1[ci] = *(const f4*)p1;
    }
#pragma unroll
    for (int rr = 0; rr < 8; ++rr) {
      const int rl = rh * 8 + rr;
      const int row = (rl & 3) * 1024 + jbase + (rl >> 2);
      const f4* wih = (const f4*)(d_wih + (size_t)row * 1536);
      const f4* whh = (const f4*)(d_whh + (size_t)row * 1024);
#pragma unroll
      for (int ci = 0; ci < 5; ++ci) {
        const int c = h * 5 + ci;
        f4 w = (c < 6) ? wih[l + 64 * c] : whh[l + 64 * c - 384];
        a0[rr] = dot4(w, x0[ci], a0[rr]);
        a1[rr] = dot4(w, x1[ci], a1[rr]);
      }
    }
  }
#pragma unroll
  for (int rr = 0; rr < 8; ++rr) {
    float s0 = wave_sum(a0[rr]);
    float s1 = wave_sum(a1[rr]);
    if (l == 0) {
      gates[(rh * 8 + rr) * 16 + b0] = s0;
      gates[(rh * 8 + rr) * 16 + b1] = s1;
    }
  }
}

__device__ __forceinline__ void lstm_pointwise(const float* __restrict__ gates,
    const float* __restrict__ bias, float* __restrict__ cst, float* __restrict__ hout,
    int tid64, int jbase) {
  const int jl = tid64 >> 4, b = tid64 & 15;
  const int J = jbase + jl;
  const int ci = b * 1024 + J;
  const float iv = gates[(jl * 4 + 0) * 16 + b] + bias[J];
  const float fv = gates[(jl * 4 + 1) * 16 + b] + bias[1024 + J];
  const float gv = gates[(jl * 4 + 2) * 16 + b] + bias[2048 + J];
  const float ov = gates[(jl * 4 + 3) * 16 + b] + bias[3072 + J];
  const float c2 = sigm(fv) * cst[ci] + sigm(iv) * tanhf(gv);
  cst[ci] = c2;
  hout[ci] = sigm(ov) * tanhf(c2);
}

// proj: out[m,t] for one batch, K=1536 = [dh 1024 | actx 512], wave-split 5 m-rows/wave
__device__ __forceinline__ void project(int tid, int b,
    const float* __restrict__ dhb, const float* __restrict__ axb,
    const float* __restrict__ proj_w, const float* __restrict__ proj_b,
    float* __restrict__ out, int tout) {
  const int wid = tid >> 6, l = tid & 63;
  f4 xp[6];
#pragma unroll
  for (int c = 0; c < 6; ++c) {
    const int kf = l + 64 * c;
    const float* p = (c < 4) ? dhb + kf * 4 : axb + (kf - 256) * 4;
    xp[c] = *(const f4*)p;
  }
#pragma unroll
  for (int mi = 0; mi < 5; ++mi) {
    const int m = wid * 5 + mi;
    const f4* wr = (const f4*)(proj_w + (size_t)m * 1536);
    float s = 0.f;
#pragma unroll
    for (int c = 0; c < 6; ++c) s = dot4(wr[l + 64 * c], xp[c], s);
    s = wave_sum(s);
    if (l == 0) out[(size_t)b * 16000 + m * 200 + tout] = s + proj_b[m];
  }
}

__global__ __launch_bounds__(TPB, 1) void decoder_persistent_kernel(
    const float* __restrict__ memory, const float* __restrict__ dec_inp,
    const int* __restrict__ mem_len,
    const float* __restrict__ pw1, const float* __restrict__ pw2,
    const float* __restrict__ a_wih, const float* __restrict__ a_whh, const float* __restrict__ a_b,
    const float* __restrict__ d_wih, const float* __restrict__ d_whh, const float* __restrict__ d_b,
    const float* __restrict__ proj_w, const float* __restrict__ proj_b,
    const float* __restrict__ query_w, const float* __restrict__ memory_w,
    const float* __restrict__ v_w, const float* __restrict__ conv_w, const float* __restrict__ ldw,
    float* __restrict__ out, float* __restrict__ ws) {
  __shared__ float attn[7168];     // attention persistent state+weights (blocks 0..15)
  __shared__ float gatesA[256];
  __shared__ float gatesC[256];
  __shared__ float sm_xin[4 * 80];
  __shared__ float sm_h1[4 * 256];

  unsigned* bar = (unsigned*)ws;
  float* ah      = ws + WS_AH;
  float* ac      = ws + WS_AC;
  float* dh      = ws + WS_DH;
  float* dc      = ws + WS_DC;
  float* actx    = ws + WS_ACTX;
  float* dec_ins = ws + WS_DEC;
  float* pmem    = ws + WS_PMEM;

  const int tid = threadIdx.x;
  const int jbase = blockIdx.x * 4;

  // ---------------- P0a: prenet -> dec_ins [200*16][256], 4 tasks/block-iter ----------------
  {
    uint32_t d00, d01, d10, d11;
    tf2x32(0u, 42u, 0u, 0u, d00, d01);
    tf2x32(0u, 42u, 0u, 1u, d10, d11);
    const int s = tid >> 8, st = tid & 255;
    float* xin = sm_xin + s * 80;
    float* h1  = sm_h1 + s * 256;
    for (int base = blockIdx.x * 4; base < 3200; base += NB * 4) {
      const int task = base + s;
      const int tt = task >> 4, b = task & 15;
      if (st < 80) xin[st] = (tt == 0) ? 0.f : dec_inp[(size_t)b * 16000 + st * 200 + (tt - 1)];
      __syncthreads();
      float acc = 0.f;
      const float* w1r = pw1 + st * 80;
#pragma unroll 4
      for (int mm = 0; mm < 80; ++mm) acc = fmaf(xin[mm], w1r[mm], acc);
      acc = fmaxf(acc, 0.f);
      const uint32_t idx = (uint32_t)task * 256u + (uint32_t)st;
      acc = (tf_fold(d00, d01, idx) >> 31) ? 0.f : acc * 2.f;
      h1[st] = acc;
      __syncthreads();
      float acc2 = 0.f;
      const float* w2r = pw2 + st * 256;
#pragma unroll 4
      for (int pp = 0; pp < 256; ++pp) acc2 = fmaf(h1[pp], w2r[pp], acc2);
      acc2 = fmaxf(acc2, 0.f);
      acc2 = (tf_fold(d10, d11, idx) >> 31) ? 0.f : acc2 * 2.f;
      dec_ins[(size_t)task * 256 + st] = acc2;
      __syncthreads();
    }
  }
  // ---------------- P0b: pmem = memory @ memory_w.T  [16*256][128], 8 tasks/iter ----------------
  {
    const int s = tid >> 7, st = tid & 127;
    for (int base = blockIdx.x * 8; base < 4096; base += NB * 8) {
      const int task = base + s;
      pmem[(size_t)task * 128 + st] =
          dot_f4(memory + (size_t)task * 512, memory_w + (size_t)st * 512, 128);
    }
  }
  grid_sync(bar);

  // ---------------- prologue: A(0) ----------------
  lstmA_gates(tid, jbase, dec_ins, actx + 8192, ah + 16384, a_wih, a_whh, gatesA);
  __syncthreads();
  if (tid < 64) lstm_pointwise(gatesA, a_b, ac, ah /*parity 0*/, tid, jbase);
  grid_sync(bar);

  // ---------------- 200 steps: phase1 = B(t)+proj(t-1); phase2 = C(t)+A(t+1) ----------------
  for (int t = 0; t < 200; ++t) {
    const int cur = t & 1, prv = cur ^ 1;

    // ---- phase1 ----
    if (blockIdx.x < 16) {
      const int b = blockIdx.x;
      float* aw_s  = attn;
      float* awc_s = attn + 256;
      float* convw = attn + 512;    // [(c*31+k)*32 + o]
      float* ldw_s = attn + 2496;   // [128][32]
      float* vw_s  = attn + 6592;
      float* q_s   = attn + 6720;
      float* epair = attn + 6848;
      float* red_s = attn + 7104;
      if (t == 0) {
        for (int i = tid; i < 1984; i += TPB) { int o = i & 31, ck = i >> 5; convw[i] = conv_w[o * 62 + ck]; }
        for (int i = tid; i < 4096; i += TPB) ldw_s[i] = ldw[i];
        if (tid < 128) vw_s[tid] = v_w[tid];
        if (tid < 256) { aw_s[tid] = 0.f; awc_s[tid] = 0.f; }
      }
      __syncthreads();
      // query = ah_new @ query_w.T (wave-split, 8 rows/wave)
      {
        const int wid = tid >> 6, l = tid & 63;
        f4 xq[4];
#pragma unroll
        for (int c = 0; c < 4; ++c)
          xq[c] = *(const f4*)(ah + cur * 16384 + b * 1024 + (l + 64 * c) * 4);
#pragma unroll
        for (int ai = 0; ai < 8; ++ai) {
          const int a = wid * 8 + ai;
          const f4* wr = (const f4*)(query_w + (size_t)a * 1024);
          float s = 0.f;
#pragma unroll
          for (int c = 0; c < 4; ++c) s = dot4(wr[l + 64 * c], xq[c], s);
          s = wave_sum(s);
          if (l == 0) q_s[a] = s;
        }
      }
      __syncthreads();
      if (tid < 256) {
        const int half = tid >> 7, tt = 128 + (tid & 127);
        float loc[32];
#pragma unroll
        for (int o = 0; o < 32; ++o) loc[o] = 0.f;
        for (int c = 0; c < 2; ++c) {
          const float* src = c ? awc_s : aw_s;
          for (int k = 0; k < 31; ++k) {
            const int p = tt - 15 + k;
            const float v = (p < 256) ? src[p] : 0.f;
            const float* wr = convw + (c * 31 + k) * 32;
#pragma unroll
            for (int o = 0; o < 32; ++o) loc[o] = fmaf(v, wr[o], loc[o]);
          }
        }
        float e = 0.f;
        const float* pm = pmem + ((size_t)(b * 256 + tt)) * 128 + half * 64;
        const float* qh = q_s + half * 64;
        const float* vh = vw_s + half * 64;
        for (int a = 0; a < 64; ++a) {
          const float* lr = ldw_s + (half * 64 + a) * 32;
          float locd = 0.f;
#pragma unroll
          for (int o = 0; o < 32; ++o) locd = fmaf(loc[o], lr[o], locd);
          float s = qh[a] + locd + pm[a];
          s = fminf(20.f, fmaxf(-20.f, s));
          e = fmaf(tanhf(s), vh[a], e);
        }
        epair[tid] = e;
      }
      __syncthreads();
      const int lenb = mem_len[b];
      float e = 0.f, p = 0.f; bool live = false;
      if (tid < 128) { e = epair[tid] + epair[tid + 128]; live = (128 + tid) >= lenb; }
      if (tid < 256) {
        float sc = live ? e : -3.4e38f;
#pragma unroll
        for (int off = 32; off; off >>= 1) sc = fmaxf(sc, __shfl_xor(sc, off, 64));
        if ((tid & 63) == 0) red_s[tid >> 6] = sc;
      }
      __syncthreads();
      if (tid < 256) {
        const float mx = fmaxf(fmaxf(red_s[0], red_s[1]), fmaxf(red_s[2], red_s[3]));
        p = live ? expf(e - mx) : 0.f;
        float z = p;
#pragma unroll
        for (int off = 32; off; off >>= 1) z += __shfl_xor(z, off, 64);
        if ((tid & 63) == 0) red_s[4 + (tid >> 6)] = z;
      }
      __syncthreads();
      if (tid < 128) {
        const float z = red_s[4] + red_s[5] + red_s[6] + red_s[7];
        const float awv = p / z;
        aw_s[128 + tid] = awv;
        awc_s[128 + tid] += awv;
      }
      __syncthreads();
      if (tid < 512) {
        const int e0 = tid;
        float acc2 = 0.f;
#pragma unroll 4
        for (int tt2 = lenb; tt2 < 256; ++tt2)
          acc2 = fmaf(aw_s[tt2], memory[((size_t)(b * 256 + tt2)) * 512 + e0], acc2);
        actx[cur * 8192 + b * 512 + e0] = acc2;
      }
    } else if (blockIdx.x < 32) {
      if (t > 0) {
        const int b = blockIdx.x - 16;
        project(tid, b, dh + prv * 16384 + b * 1024, actx + prv * 8192 + b * 512,
                proj_w, proj_b, out, t - 1);
      }
    }
    grid_sync(bar);

    // ---- phase2: C(t) and A(t+1) ----
    lstmC_gates(tid, jbase, ah + cur * 16384, actx + cur * 8192, dh + prv * 16384,
                d_wih, d_whh, gatesC);
    if (t < 199)
      lstmA_gates(tid, jbase, dec_ins + (size_t)(t + 1) * 4096, actx + cur * 8192,
                  ah + cur * 16384, a_wih, a_whh, gatesA);
    __syncthreads();
    if (tid < 64) {
      lstm_pointwise(gatesC, d_b, dc, dh + cur * 16384, tid, jbase);
    } else if (tid < 128 && t < 199) {
      lstm_pointwise(gatesA, a_b, ac, ah + prv * 16384, tid - 64, jbase);
    }
    grid_sync(bar);
  }

  // ---- final projection t = 199 (parity 1) ----
  if (blockIdx.x >= 16 && blockIdx.x < 32) {
    const int b = blockIdx.x - 16;
    project(tid, b, dh + 16384 + b * 1024, actx + 8192 + b * 512, proj_w, proj_b, out, 199);
  }
}

extern "C" void kernel_launch(void* const* d_in, const int* in_sizes, int n_in,
                              void* d_out, int out_size, void* d_ws, size_t ws_size,
                              hipStream_t stream) {
  (void)in_sizes; (void)n_in; (void)out_size; (void)ws_size;
  const float* memory   = (const float*)d_in[0];
  const float* dec_inp  = (const float*)d_in[1];
  const int*   mem_len  = (const int*)d_in[2];
  const float* pw1      = (const float*)d_in[3];
  const float* pw2      = (const float*)d_in[4];
  const float* a_wih    = (const float*)d_in[5];
  const float* a_whh    = (const float*)d_in[6];
  const float* a_b      = (const float*)d_in[7];
  const float* d_wih    = (const float*)d_in[8];
  const float* d_whh    = (const float*)d_in[9];
  const float* d_b      = (const float*)d_in[10];
  const float* proj_w   = (const float*)d_in[11];
  const float* proj_b   = (const float*)d_in[12];
  const float* query_w  = (const float*)d_in[13];
  const float* memory_w = (const float*)d_in[14];
  const float* v_w      = (const float*)d_in[15];
  const float* conv_w   = (const float*)d_in[16];
  const float* ldw      = (const float*)d_in[17];

  hipMemsetAsync(d_ws, 0, WS_STATE_BYTES, stream);
  decoder_persistent_kernel<<<NB, TPB, 0, stream>>>(
      memory, dec_inp, mem_len, pw1, pw2, a_wih, a_whh, a_b,
      d_wih, d_whh, d_b, proj_w, proj_b, query_w, memory_w, v_w, conv_w, ldw,
      (float*)d_out, (float*)d_ws);
}

// Round 6
// 63237.048 us; speedup vs baseline: 3.6807x; 3.6807x over previous
//
#include <hip/hip_runtime.h>
#include <cstdint>
#include <cstddef>

#define TPB 1024
#define NB  256

typedef float4 f4;
typedef float f32x4 __attribute__((ext_vector_type(4)));
typedef short short8 __attribute__((ext_vector_type(8)));

// ---------------- ws float offsets ----------------
#define O_BAR    0
#define O_AH     16        // f32 [16][1024]
#define O_AC     16400
#define O_DH     32784
#define O_DC     49168
#define O_ACTX   65552     // f32 [2][16][512]
#define O_AW     81936     // f32 [16][256]
#define O_AWC    86032
#define O_XC     90128     // bf16 [2][320][16][8]   (ah | actx | dh)   parity-buffered
#define O_XAA    131088    // bf16 [2][192][16][8]   (actx | ah)        parity-buffered
#define O_EWS    155664    // f32 [2][16][256]
#define O_DECFR  163856    // bf16 [200][32][16][8]
#define O_PMEM   573456    // f32 [4096][128]
#define O_LDWBF  1097744   // bf16 [128][32]
#define O_CONVWT 1099792   // f32 [62][32]
#define ZERO_BYTES (O_EWS * 4)   // zero: barrier + f32 state + both xC/xAa parities

#define XC_PAR  40960      // shorts per parity copy
#define XAA_PAR 24576

// LDS weight-row swizzle (T2): 16B-granular XOR, bijective (row lengths % 64 == 0)
#define SWZ(n, k) ((k) ^ (((n) & 7) << 3))

// ---------------- JAX Threefry-2x32 (partitionable) ----------------
__device__ __forceinline__ void tf2x32(uint32_t k0, uint32_t k1, uint32_t x0, uint32_t x1,
                                       uint32_t& o0, uint32_t& o1) {
  uint32_t ks2 = k0 ^ k1 ^ 0x1BD11BDAu;
  x0 += k0; x1 += k1;
#define TFR(r) { x0 += x1; x1 = (x1 << (r)) | (x1 >> (32 - (r))); x1 ^= x0; }
  TFR(13) TFR(15) TFR(26) TFR(6)
  x0 += k1;  x1 += ks2 + 1u;
  TFR(17) TFR(29) TFR(16) TFR(24)
  x0 += ks2; x1 += k0 + 2u;
  TFR(13) TFR(15) TFR(26) TFR(6)
  x0 += k0;  x1 += k1 + 3u;
  TFR(17) TFR(29) TFR(16) TFR(24)
  x0 += k1;  x1 += ks2 + 4u;
  TFR(13) TFR(15) TFR(26) TFR(6)
  x0 += ks2; x1 += k0 + 5u;
#undef TFR
  o0 = x0; o1 = x1;
}
__device__ __forceinline__ uint32_t tf_fold(uint32_t k0, uint32_t k1, uint32_t idx) {
  uint32_t a, b; tf2x32(k0, k1, 0u, idx, a, b); return a ^ b;
}

// ---------------- helpers ----------------
__device__ __forceinline__ unsigned short f2bf(float x) {   // RNE fp32->bf16
  uint32_t u = __float_as_uint(x);
  u += 0x7fffu + ((u >> 16) & 1u);
  return (unsigned short)(u >> 16);
}
__device__ __forceinline__ float dot4(f4 a, f4 b, float acc) {
  acc = fmaf(a.x, b.x, acc); acc = fmaf(a.y, b.y, acc);
  acc = fmaf(a.z, b.z, acc); acc = fmaf(a.w, b.w, acc);
  return acc;
}
__device__ __forceinline__ float dot_f4(const float* __restrict__ x, const float* __restrict__ w, int n4) {
  const f4* xv = (const f4*)x; const f4* wv = (const f4*)w;
  float s = 0.f;
#pragma unroll 8
  for (int k = 0; k < n4; ++k) s = dot4(xv[k], wv[k], s);
  return s;
}
__device__ __forceinline__ float sigm(float x) { return 1.f / (1.f + expf(-x)); }
__device__ __forceinline__ float wave_sum(float s) {
#pragma unroll
  for (int off = 32; off; off >>= 1) s += __shfl_xor(s, off, 64);
  return s;
}
__device__ __forceinline__ float wave_max(float s) {
#pragma unroll
  for (int off = 32; off; off >>= 1) s = fmaxf(s, __shfl_xor(s, off, 64));
  return s;
}
__device__ __forceinline__ void grid_sync(unsigned* bar) {
  __syncthreads();
  if (threadIdx.x == 0) {
    __threadfence();
    unsigned g = __hip_atomic_load(bar + 1, __ATOMIC_RELAXED, __HIP_MEMORY_SCOPE_AGENT);
    unsigned a = __hip_atomic_fetch_add(bar, 1u, __ATOMIC_ACQ_REL, __HIP_MEMORY_SCOPE_AGENT);
    if (a == (unsigned)(NB - 1)) {
      __hip_atomic_store(bar, 0u, __ATOMIC_RELAXED, __HIP_MEMORY_SCOPE_AGENT);
      __hip_atomic_store(bar + 1, g + 1u, __ATOMIC_RELEASE, __HIP_MEMORY_SCOPE_AGENT);
    } else {
      while (__hip_atomic_load(bar + 1, __ATOMIC_ACQUIRE, __HIP_MEMORY_SCOPE_AGENT) == g)
        __builtin_amdgcn_s_sleep(1);
    }
  }
  __syncthreads();
}

// projection: out[m, tout] for one batch; K = 1536 = [dh 1024 | actx 512]
__device__ __forceinline__ void project(int tid, int b,
    const float* __restrict__ dhb, const float* __restrict__ axb,
    const float* __restrict__ proj_w, const float* __restrict__ proj_b,
    float* __restrict__ out, int tout) {
  const int wid = tid >> 6, l = tid & 63;
  f4 xp[6];
#pragma unroll
  for (int c = 0; c < 6; ++c) {
    const int kf = l + 64 * c;
    const float* p = (c < 4) ? dhb + kf * 4 : axb + (kf - 256) * 4;
    xp[c] = *(const f4*)p;
  }
#pragma unroll
  for (int mi = 0; mi < 5; ++mi) {
    const int m = wid * 5 + mi;
    const f4* wr = (const f4*)(proj_w + (size_t)m * 1536);
    float s = 0.f;
#pragma unroll
    for (int c = 0; c < 6; ++c) s = dot4(wr[l + 64 * c], xp[c], s);
    s = wave_sum(s);
    if (l == 0) out[(size_t)b * 16000 + m * 200 + tout] = s + proj_b[m];
  }
}

__global__ __launch_bounds__(TPB, 4) void decoder_persistent_kernel(
    const float* __restrict__ memory, const float* __restrict__ dec_inp,
    const int* __restrict__ mem_len,
    const float* __restrict__ pw1, const float* __restrict__ pw2,
    const float* __restrict__ a_wih, const float* __restrict__ a_whh, const float* __restrict__ a_b,
    const float* __restrict__ d_wih, const float* __restrict__ d_whh, const float* __restrict__ d_b,
    const float* __restrict__ proj_w, const float* __restrict__ proj_b,
    const float* __restrict__ query_w, const float* __restrict__ memory_w,
    const float* __restrict__ v_w, const float* __restrict__ conv_w, const float* __restrict__ ldw,
    float* __restrict__ out, float* __restrict__ wsf) {
  // LDS: per-block bf16 weights resident across all 200 steps + scratch union
  __shared__ __align__(16) unsigned short Wc_sh[16 * 2568];  // 82,176 B (swizzled rows)
  __shared__ __align__(16) unsigned short Wa_sh[16 * 1800];  // 57,600 B (swizzled rows)
  __shared__ __align__(16) float scr[4096];                  // 16,384 B scratch union

  unsigned* bar = (unsigned*)wsf;
  const int tid = threadIdx.x;
  const int bid = blockIdx.x;
  const int jbase = bid * 4;

  unsigned short* xC  = (unsigned short*)(wsf + O_XC);
  unsigned short* xAa = (unsigned short*)(wsf + O_XAA);
  unsigned short* decfr = (unsigned short*)(wsf + O_DECFR);
  unsigned short* ldwbf = (unsigned short*)(wsf + O_LDWBF);
  float* convwt = wsf + O_CONVWT;
  float* pmem   = wsf + O_PMEM;

  // ================= PROLOGUE =================
  // P0a: prenet -> decfr bf16 frag layout [tt][k8][b][e]
  {
    uint32_t d00, d01, d10, d11;
    tf2x32(0u, 42u, 0u, 0u, d00, d01);
    tf2x32(0u, 42u, 0u, 1u, d10, d11);
    const int s = tid >> 8, st = tid & 255;
    float* xin = scr + s * 336;
    float* h1  = scr + s * 336 + 80;
    for (int base = bid * 4; base < 3200; base += NB * 4) {
      const int task = base + s;
      const int tt = task >> 4, b = task & 15;
      if (st < 80) xin[st] = (tt == 0) ? 0.f : dec_inp[(size_t)b * 16000 + st * 200 + (tt - 1)];
      __syncthreads();
      float acc = 0.f;
      const float* w1r = pw1 + st * 80;
#pragma unroll 4
      for (int mm = 0; mm < 80; ++mm) acc = fmaf(xin[mm], w1r[mm], acc);
      acc = fmaxf(acc, 0.f);
      const uint32_t idx = (uint32_t)task * 256u + (uint32_t)st;
      acc = (tf_fold(d00, d01, idx) >> 31) ? 0.f : acc * 2.f;
      h1[st] = acc;
      __syncthreads();
      float acc2 = 0.f;
      const float* w2r = pw2 + st * 256;
#pragma unroll 4
      for (int pp = 0; pp < 256; ++pp) acc2 = fmaf(h1[pp], w2r[pp], acc2);
      acc2 = fmaxf(acc2, 0.f);
      acc2 = (tf_fold(d10, d11, idx) >> 31) ? 0.f : acc2 * 2.f;
      decfr[(size_t)tt * 4096 + (st >> 3) * 128 + b * 8 + (st & 7)] = f2bf(acc2);
      __syncthreads();
    }
  }
  // P0b: pmem = memory @ memory_w.T
  {
    const int s = tid >> 7, st = tid & 127;
    for (int base = bid * 8; base < 4096; base += NB * 8) {
      const int task = base + s;
      pmem[(size_t)task * 128 + st] =
          dot_f4(memory + (size_t)task * 512, memory_w + (size_t)st * 512, 128);
    }
  }
  // P0c: weights -> LDS bf16, swizzled (rows n = jloc*4 + g <-> global row g*1024 + jbase + jloc)
  for (int n = 0; n < 16; ++n) {
    const int g = n & 3, jl = n >> 2;
    const int row = g * 1024 + jbase + jl;
    const float* wC1 = d_wih + (size_t)row * 1536;
    const float* wC2 = d_whh + (size_t)row * 1024;
    for (int k = tid; k < 2560; k += TPB)
      Wc_sh[n * 2568 + SWZ(n, k)] = f2bf(k < 1536 ? wC1[k] : wC2[k - 1536]);
    const float* wA1 = a_wih + (size_t)row * 768;
    const float* wA2 = a_whh + (size_t)row * 1024;
    for (int k = tid; k < 1792; k += TPB)
      Wa_sh[n * 1800 + SWZ(n, k)] = f2bf(k < 768 ? wA1[k] : wA2[k - 768]);
  }
  // P0d: small weight copies
  if (bid == 0) for (int i = tid; i < 4096; i += TPB) ldwbf[i] = f2bf(ldw[i]);
  if (bid == 1) for (int i = tid; i < 1984; i += TPB) {
    const int o = i & 31, ck = i >> 5;
    convwt[ck * 32 + o] = conv_w[o * 62 + ck];
  }
  grid_sync(bar);

  // ================= MAIN LOOP (t = -1 runs A(0) only) =================
  for (int t = -1; t < 200; ++t) {
    if (t >= 0) {
      // ---- P1: distributed attention energies (blocks 0..31: b x a-half) ----
      if (bid < 32) {
        const int b = bid >> 1, ahalf = bid & 1;
        float* awst  = scr;              // [2][160]  aw/awc window p=113..272
        float* q_s   = scr + 320;        // [64]
        float* e_red = scr + 384;        // [2][128]
        unsigned short* loc_s = (unsigned short*)(scr + 640);  // [128][40] bf16
        if (tid < 320) {
          const int c2 = tid / 160, j = tid % 160, p = 113 + j;
          awst[c2 * 160 + j] = (p < 256) ? wsf[(c2 ? O_AWC : O_AW) + b * 256 + p] : 0.f;
        }
        __syncthreads();
        // conv: thread = (ttl 0..127, og 0..7 -> 4 filters)
        {
          const int ttl = tid >> 3, o0 = (tid & 7) * 4;
          float l0 = 0.f, l1 = 0.f, l2 = 0.f, l3 = 0.f;
#pragma unroll
          for (int c2 = 0; c2 < 2; ++c2) {
            const float* src = awst + c2 * 160 + ttl;        // src[k] = window[tt-15+k]
            const float* wp  = convwt + (c2 * 31) * 32 + o0;
#pragma unroll
            for (int k = 0; k < 31; ++k) {
              const float v = src[k];
              const f4 wv = *(const f4*)(wp + k * 32);
              l0 = fmaf(v, wv.x, l0); l1 = fmaf(v, wv.y, l1);
              l2 = fmaf(v, wv.z, l2); l3 = fmaf(v, wv.w, l3);
            }
          }
          unsigned short* lp = loc_s + ttl * 40 + o0;
          lp[0] = f2bf(l0); lp[1] = f2bf(l1); lp[2] = f2bf(l2); lp[3] = f2bf(l3);
        }
        // query: 16 waves x 4 rows (this block's 64-a half only)
        {
          const int w = tid >> 6, l = tid & 63;
          f4 xq[4];
#pragma unroll
          for (int c = 0; c < 4; ++c)
            xq[c] = *(const f4*)(wsf + O_AH + b * 1024 + (l + 64 * c) * 4);
#pragma unroll
          for (int i = 0; i < 4; ++i) {
            const int al = w * 4 + i;
            const int ag = ahalf * 64 + al;
            const f4* wr = (const f4*)(query_w + (size_t)ag * 1024);
            float s = 0.f;
#pragma unroll
            for (int c = 0; c < 4; ++c) s = dot4(wr[l + 64 * c], xq[c], s);
            s = wave_sum(s);
            if (l == 0) q_s[al] = s;
          }
        }
        __syncthreads();
        // dense via MFMA: wave w -> ttile = w>>1, atiles = (w&1)*2 + {0,1}
        {
          const int w = tid >> 6, l = tid & 63, q = l >> 4, c = l & 15;
          const int ttile = w >> 1;
          const short8 af = *(const short8*)(loc_s + (ttile * 16 + c) * 40 + q * 8);
          float eacc[4] = {0.f, 0.f, 0.f, 0.f};
#pragma unroll
          for (int at = 0; at < 2; ++at) {
            const int atile = (w & 1) * 2 + at;
            const int al = atile * 16 + c;
            const int ag = ahalf * 64 + al;
            const short8 bf = *(const short8*)(ldwbf + ag * 32 + q * 8);
            f32x4 d = {0.f, 0.f, 0.f, 0.f};
            d = __builtin_amdgcn_mfma_f32_16x16x32_bf16(af, bf, d, 0, 0, 0);
            const float qa = q_s[al];
            const float vv = v_w[ag];
#pragma unroll
            for (int r = 0; r < 4; ++r) {
              const int tt = 128 + ttile * 16 + 4 * q + r;
              float s = d[r] + qa + pmem[(size_t)(b * 256 + tt) * 128 + ag];
              s = fminf(20.f, fmaxf(-20.f, s));
              eacc[r] = fmaf(tanhf(s), vv, eacc[r]);
            }
          }
#pragma unroll
          for (int r = 0; r < 4; ++r) {
            float e = eacc[r];
            e += __shfl_xor(e, 1, 64); e += __shfl_xor(e, 2, 64);
            e += __shfl_xor(e, 4, 64); e += __shfl_xor(e, 8, 64);
            if (c == 0) e_red[(w & 1) * 128 + ttile * 16 + 4 * q + r] = e;
          }
        }
        __syncthreads();
        if (tid < 128)
          wsf[O_EWS + ahalf * 4096 + b * 256 + 128 + tid] = e_red[tid] + e_red[128 + tid];
      }
      grid_sync(bar);

      // ---- P2: softmax + actx (blocks 0..15) | projection t-1 (16..31) ----
      if (bid < 16) {
        const int b = bid;
        float* red8  = scr;          // [16]
        float* awv_s = scr + 16;     // [128]
        float* part  = scr + 160;    // [2][512]
        const int lenb = mem_len[b];
        float e = 0.f; bool live = false;
        if (tid < 128) {
          const int tt = 128 + tid;
          live = tt >= lenb;
          e = wsf[O_EWS + b * 256 + tt] + wsf[O_EWS + 4096 + b * 256 + tt];
        }
        if (tid < 128) {
          float m = live ? e : -3.4e38f;
          m = wave_max(m);
          if ((tid & 63) == 0) red8[tid >> 6] = m;
        }
        __syncthreads();
        const float mx = fmaxf(red8[0], red8[1]);
        float p = 0.f;
        if (tid < 128) {
          p = live ? expf(e - mx) : 0.f;
          float z = wave_sum(p);
          if ((tid & 63) == 0) red8[2 + (tid >> 6)] = z;
        }
        __syncthreads();
        if (tid < 128) {
          const float z = red8[2] + red8[3];
          const float awv = live ? p / z : 0.f;
          awv_s[tid] = awv;
          wsf[O_AW + b * 256 + 128 + tid] = awv;
          if (live) wsf[O_AWC + b * 256 + 128 + tid] += awv;
        }
        __syncthreads();
        {
          const int th = tid >> 9, e0 = tid & 511;
          float a = 0.f;
#pragma unroll 4
          for (int j = 0; j < 64; ++j) {
            const int tt = 128 + th * 64 + j;
            a = fmaf(awv_s[th * 64 + j], memory[((size_t)(b * 256 + tt)) * 512 + e0], a);
          }
          part[th * 512 + e0] = a;
        }
        __syncthreads();
        if (tid < 512) {
          const float a = part[tid] + part[512 + tid];
          wsf[O_ACTX + (t & 1) * 8192 + b * 512 + tid] = a;
          const unsigned short ab = f2bf(a);
          unsigned short* xCp = xC  + (t & 1) * XC_PAR;
          unsigned short* xAp = xAa + (t & 1) * XAA_PAR;
          xCp[(128 + (tid >> 3)) * 128 + b * 8 + (tid & 7)] = ab;
          xAp[((tid >> 3)) * 128 + b * 8 + (tid & 7)] = ab;
        }
      } else if (bid < 32 && t > 0) {
        const int b = bid - 16;
        project(tid, b, wsf + O_DH + b * 1024,
                wsf + O_ACTX + ((t - 1) & 1) * 8192 + b * 512, proj_w, proj_b, out, t - 1);
      }
      grid_sync(bar);
    }

    // ---- P3: C(t) MFMA (waves 0..7) + A(t+1) MFMA (waves 8..15) + pointwise ----
    {
      const int rp = t & 1;            // read parity  (t = -1 -> 1, zeros)
      const int wp2 = rp ^ 1;          // write parity (next step's inputs)
      const unsigned short* xCr = xC  + rp * XC_PAR;
      const unsigned short* xAr = xAa + rp * XAA_PAR;
      unsigned short* xCw = xC  + wp2 * XC_PAR;
      unsigned short* xAw = xAa + wp2 * XAA_PAR;
      float* redC = scr;          // [8][256]
      float* redA = scr + 2048;   // [8][256]
      const int w = tid >> 6, l = tid & 63;
      const int q = l >> 4, c = l & 15;
      if (w < 8) {
        if (t >= 0) {
          f32x4 acc = {0.f, 0.f, 0.f, 0.f};
#pragma unroll
          for (int i = 0; i < 10; ++i) {
            const int k32 = w * 10 + i;
            const short8 af = *(const short8*)(xCr + k32 * 512 + l * 8);
            const short8 bf = *(const short8*)(Wc_sh + c * 2568 + SWZ(c, q * 8 + k32 * 32));
            acc = __builtin_amdgcn_mfma_f32_16x16x32_bf16(af, bf, acc, 0, 0, 0);
          }
#pragma unroll
          for (int r = 0; r < 4; ++r) redC[w * 256 + (4 * q + r) * 16 + c] = acc[r];
        }
      } else {
        if (t < 199) {
          const unsigned short* dfr = decfr + (size_t)(t + 1) * 4096;
          f32x4 acc = {0.f, 0.f, 0.f, 0.f};
#pragma unroll
          for (int i = 0; i < 7; ++i) {
            const int k32 = (w - 8) * 7 + i;
            const unsigned short* src = (k32 < 8) ? (dfr + k32 * 512) : (xAr + (k32 - 8) * 512);
            const short8 af = *(const short8*)(src + l * 8);
            const short8 bf = *(const short8*)(Wa_sh + c * 1800 + SWZ(c, q * 8 + k32 * 32));
            acc = __builtin_amdgcn_mfma_f32_16x16x32_bf16(af, bf, acc, 0, 0, 0);
          }
#pragma unroll
          for (int r = 0; r < 4; ++r) redA[(w - 8) * 256 + (4 * q + r) * 16 + c] = acc[r];
        }
      }
      __syncthreads();
      if (tid < 64) {
        if (t >= 0) {            // C pointwise
          const int b = tid >> 2, jl = tid & 3, J = jbase + jl;
          float gv[4];
#pragma unroll
          for (int g = 0; g < 4; ++g) {
            float s = d_b[g * 1024 + J];
#pragma unroll
            for (int w2 = 0; w2 < 8; ++w2) s += redC[w2 * 256 + b * 16 + (jl * 4 + g)];
            gv[g] = s;
          }
          const int bi = b * 1024 + J;
          const float c2v = sigm(gv[1]) * wsf[O_DC + bi] + sigm(gv[0]) * tanhf(gv[2]);
          wsf[O_DC + bi] = c2v;
          const float h = sigm(gv[3]) * tanhf(c2v);
          wsf[O_DH + bi] = h;
          xCw[(192 + (J >> 3)) * 128 + b * 8 + (J & 7)] = f2bf(h);
        }
      } else if (tid < 128) {
        if (t < 199) {           // A(t+1) pointwise
          const int t2 = tid - 64;
          const int b = t2 >> 2, jl = t2 & 3, J = jbase + jl;
          float gv[4];
#pragma unroll
          for (int g = 0; g < 4; ++g) {
            float s = a_b[g * 1024 + J];
#pragma unroll
            for (int w2 = 0; w2 < 8; ++w2) s += redA[w2 * 256 + b * 16 + (jl * 4 + g)];
            gv[g] = s;
          }
          const int bi = b * 1024 + J;
          const float c2v = sigm(gv[1]) * wsf[O_AC + bi] + sigm(gv[0]) * tanhf(gv[2]);
          wsf[O_AC + bi] = c2v;
          const float h = sigm(gv[3]) * tanhf(c2v);
          wsf[O_AH + bi] = h;
          const unsigned short hb = f2bf(h);
          xCw[((J >> 3)) * 128 + b * 8 + (J & 7)] = hb;
          xAw[(64 + (J >> 3)) * 128 + b * 8 + (J & 7)] = hb;
        }
      }
    }
    grid_sync(bar);
  }

  // ---- final projection t = 199 (parity of t=199 is 1) ----
  if (bid >= 16 && bid < 32) {
    const int b = bid - 16;
    project(tid, b, wsf + O_DH + b * 1024, wsf + O_ACTX + 8192 + b * 512,
            proj_w, proj_b, out, 199);
  }
}

extern "C" void kernel_launch(void* const* d_in, const int* in_sizes, int n_in,
                              void* d_out, int out_size, void* d_ws, size_t ws_size,
                              hipStream_t stream) {
  (void)in_sizes; (void)n_in; (void)out_size; (void)ws_size;
  const float* memory   = (const float*)d_in[0];
  const float* dec_inp  = (const float*)d_in[1];
  const int*   mem_len  = (const int*)d_in[2];
  const float* pw1      = (const float*)d_in[3];
  const float* pw2      = (const float*)d_in[4];
  const float* a_wih    = (const float*)d_in[5];
  const float* a_whh    = (const float*)d_in[6];
  const float* a_b      = (const float*)d_in[7];
  const float* d_wih    = (const float*)d_in[8];
  const float* d_whh    = (const float*)d_in[9];
  const float* d_b      = (const float*)d_in[10];
  const float* proj_w   = (const float*)d_in[11];
  const float* proj_b   = (const float*)d_in[12];
  const float* query_w  = (const float*)d_in[13];
  const float* memory_w = (const float*)d_in[14];
  const float* v_w      = (const float*)d_in[15];
  const float* conv_w   = (const float*)d_in[16];
  const float* ldw      = (const float*)d_in[17];

  hipMemsetAsync(d_ws, 0, ZERO_BYTES, stream);
  decoder_persistent_kernel<<<NB, TPB, 0, stream>>>(
      memory, dec_inp, mem_len, pw1, pw2, a_wih, a_whh, a_b,
      d_wih, d_whh, d_b, proj_w, proj_b, query_w, memory_w, v_w, conv_w, ldw,
      (float*)d_out, (float*)d_ws);
}